// Round 4
// baseline (247.843 us; speedup 1.0000x reference)
//
#include <hip/hip_runtime.h>
#include <hip/hip_cooperative_groups.h>
#include <math.h>

namespace cg = cooperative_groups;

#define SD 16512            // 128 + 128*128
#define NCH 64              // K-chunks
#define NST 516             // total k-steps of 32 (516*32 = 16512)
#define CHUNK 65536         // per-chunk partial elements (256*256)
#define LN_EPS 1e-5f

typedef __attribute__((ext_vector_type(4))) float f32x4;
typedef __attribute__((ext_vector_type(8))) short bf16x8;

__device__ __forceinline__ unsigned bfpack(float lo, float hi) {
    unsigned a = __builtin_bit_cast(unsigned, lo);
    unsigned b = __builtin_bit_cast(unsigned, hi);
    a = (a + 0x7FFFu + ((a >> 16) & 1u)) >> 16;
    b = (b + 0x7FFFu + ((b >> 16) & 1u)) >> 16;
    return a | (b << 16);
}
__device__ __forceinline__ unsigned short bf1(float x) {
    unsigned a = __builtin_bit_cast(unsigned, x);
    return (unsigned short)((a + 0x7FFFu + ((a >> 16) & 1u)) >> 16);
}

struct Args {
    const float *x, *tk, *Wd, *bd, *W2, *b2, *W1, *b1, *Wg, *bg, *Wv, *bv, *Wsk, *bs, *gamma, *beta;
    float* out;
    unsigned short* sig;
    unsigned short* xbf;
    unsigned short* WdTg;
    float* partial;
};

// ---------------------------------------------------------------------------
// One cooperative kernel, grid 256 x 512.
// Phase 1 (block b = batch b): sig[b] = [S1|S2] bf16 via MFMA; xbf; WdTg slice.
// Phase 3 (block -> (ch, mt, nt)): split-K GEMM sig @ [W2|Ws] -> partial.
// Phase 5 (block b = batch b): reduce + GRN + LN + softmax + dense MFMA -> out.
// ---------------------------------------------------------------------------
__global__ __launch_bounds__(512, 1) void k_fused(Args a) {
    __shared__ union {
        struct { unsigned short Ut[128][72]; unsigned short DXt[128][72]; float tks[64]; } p1;
        struct { unsigned short As[2][128][40]; unsigned short Bs[2][128][40]; } p3;
        struct { float hs[128], ss[128], h2s[128], red4[4][128], rtmp[2][256],
                       ys[128], es[128], wts[128]; } p5;
    } sm;

    int tid = threadIdx.x;
    int bid = blockIdx.x;
    int lane = tid & 63;
    int l15 = lane & 15, lg = lane >> 4;
    cg::grid_group grid = cg::this_grid();

    // ===================== Phase 1: signature =====================
    {
        if (tid < 64) sm.p1.tks[tid] = a.tk[tid];
        __syncthreads();
        const float* xb = a.x + (size_t)bid * 8192;
        unsigned short* xbb = a.xbf + (size_t)bid * 8192;
        int i = tid & 127, th = tid >> 7;          // th 0..3, 8 pairs each

        float x0 = sm.p1.tks[0] * xb[i];
        float xa = sm.p1.tks[th * 16] * xb[(size_t)(th * 16) * 128 + i];
        #pragma unroll
        for (int tp = 0; tp < 8; ++tp) {
            int p = th * 8 + tp;
            int t0 = 2 * p;
            float xv = sm.p1.tks[t0 + 1] * xb[(size_t)(t0 + 1) * 128 + i];
            float dx0 = xv - xa, u0 = 0.5f * (xa + xv) - x0;
            float dx1, u1, xc;
            if (p == 31) { dx1 = 0.f; u1 = 0.f; xc = 0.f; }
            else {
                xc = sm.p1.tks[t0 + 2] * xb[(size_t)(t0 + 2) * 128 + i];
                dx1 = xc - xv; u1 = 0.5f * (xv + xc) - x0;
            }
            *(unsigned*)&sm.p1.Ut[i][t0]  = bfpack(u0, u1);
            *(unsigned*)&sm.p1.DXt[i][t0] = bfpack(dx0, dx1);
            xbb[(size_t)t0 * 128 + i]       = bf1(xa);
            xbb[(size_t)(t0 + 1) * 128 + i] = bf1(xv);
            if (p == 31) a.sig[(size_t)bid * SD + i] = bf1(xv - x0);   // S1
            xa = xc;
        }
        // WdTg[d][k] for d = bid (blocks 0..127)
        if (bid < 128 && tid < 128)
            a.WdTg[(size_t)bid * 128 + tid] = bf1(a.Wd[(size_t)tid * 128 + bid]);
        __syncthreads();

        // S2 = Ut(128 x 64) @ DXt^T -> 128x128. 8 waves: 2M x 4N, tile 64x32.
        int w = tid >> 6;
        int wm = w >> 2, wn = w & 3;
        f32x4 acc[4][2];
        #pragma unroll
        for (int m = 0; m < 4; ++m)
            #pragma unroll
            for (int n = 0; n < 2; ++n) acc[m][n] = (f32x4){0.f, 0.f, 0.f, 0.f};
        #pragma unroll
        for (int ks = 0; ks < 2; ++ks) {
            bf16x8 af[4], bfv[2];
            #pragma unroll
            for (int m = 0; m < 4; ++m)
                af[m] = *(const bf16x8*)&sm.p1.Ut[wm * 64 + m * 16 + l15][ks * 32 + lg * 8];
            #pragma unroll
            for (int n = 0; n < 2; ++n)
                bfv[n] = *(const bf16x8*)&sm.p1.DXt[wn * 32 + n * 16 + l15][ks * 32 + lg * 8];
            #pragma unroll
            for (int m = 0; m < 4; ++m)
                #pragma unroll
                for (int n = 0; n < 2; ++n)
                    acc[m][n] = __builtin_amdgcn_mfma_f32_16x16x32_bf16(af[m], bfv[n], acc[m][n], 0, 0, 0);
        }
        unsigned short* sp = a.sig + (size_t)bid * SD + 128;
        #pragma unroll
        for (int m = 0; m < 4; ++m)
            #pragma unroll
            for (int n = 0; n < 2; ++n)
                #pragma unroll
                for (int rr = 0; rr < 4; ++rr)
                    sp[(size_t)(wm * 64 + m * 16 + lg * 4 + rr) * 128 + wn * 32 + n * 16 + l15]
                        = bf1(acc[m][n][rr]);
    }

    __threadfence();
    grid.sync();

    // ===================== Phase 3: split-K GEMM =====================
    {
        int ch = bid >> 2;
        int mt = (bid >> 1) & 1;
        int nt = bid & 1;
        const float* W = nt ? a.Wsk : a.W2;
        int s0  = 8 * ch + (ch > 60 ? ch - 60 : 0);
        int nst = (ch >= 60) ? 9 : 8;

        int w = tid >> 6;
        int wr = w >> 2, wc = w & 3;               // 2M x 4N waves, tile 64x32

        int arow = tid >> 2, akq = (tid & 3) * 8;  // A staging (1 uint4/thread)
        int kp = tid & 15, c4 = (tid >> 4) * 4;    // B staging (2 f32x4/thread)
        const unsigned short* sigB = a.sig + (size_t)(mt * 128) * SD;

        f32x4 acc[4][2];
        #pragma unroll
        for (int m = 0; m < 4; ++m)
            #pragma unroll
            for (int n = 0; n < 2; ++n) acc[m][n] = (f32x4){0.f, 0.f, 0.f, 0.f};

        uint4 aR;
        f32x4 bR0, bR1;

#define LOADG(s)                                                                   \
        {                                                                          \
            int kb = (s) * 32;                                                     \
            aR = *(const uint4*)(sigB + (size_t)arow * SD + kb + akq);             \
            const float* wp = W + (size_t)(kb + 2 * kp) * 128 + c4;                \
            bR0 = *(const f32x4*)wp;                                               \
            bR1 = *(const f32x4*)(wp + 128);                                       \
        }
#define WRITELDS(buf)                                                              \
        {                                                                          \
            *(uint4*)&sm.p3.As[buf][arow][akq] = aR;                               \
            _Pragma("unroll")                                                      \
            for (int j = 0; j < 4; ++j)                                            \
                *(unsigned*)&sm.p3.Bs[buf][c4 + j][2 * kp] = bfpack(bR0[j], bR1[j]); \
        }
#define COMPUTE(buf)                                                               \
        {                                                                          \
            bf16x8 af[4], bfv[2];                                                  \
            _Pragma("unroll")                                                      \
            for (int m = 0; m < 4; ++m)                                            \
                af[m] = *(const bf16x8*)&sm.p3.As[buf][wr * 64 + m * 16 + l15][lg * 8]; \
            _Pragma("unroll")                                                      \
            for (int n = 0; n < 2; ++n)                                            \
                bfv[n] = *(const bf16x8*)&sm.p3.Bs[buf][wc * 32 + n * 16 + l15][lg * 8]; \
            _Pragma("unroll")                                                      \
            for (int m = 0; m < 4; ++m)                                            \
                _Pragma("unroll")                                                  \
                for (int n = 0; n < 2; ++n)                                        \
                    acc[m][n] = __builtin_amdgcn_mfma_f32_16x16x32_bf16(af[m], bfv[n], acc[m][n], 0, 0, 0); \
        }

        LOADG(s0);
        WRITELDS(0);
        __syncthreads();
        for (int s = 0; s < nst; ++s) {
            int cur = s & 1;
            if (s < nst - 1) LOADG(s0 + s + 1);
            COMPUTE(cur);
            if (s < nst - 1) WRITELDS(cur ^ 1);
            __syncthreads();
        }
#undef LOADG
#undef WRITELDS
#undef COMPUTE

        float* Pp = a.partial + (size_t)ch * CHUNK + (size_t)(mt * 128) * 256 + nt * 128;
        #pragma unroll
        for (int m = 0; m < 4; ++m)
            #pragma unroll
            for (int n = 0; n < 2; ++n)
                #pragma unroll
                for (int rr = 0; rr < 4; ++rr)
                    Pp[(size_t)(wr * 64 + m * 16 + lg * 4 + rr) * 256 + wc * 32 + n * 16 + l15]
                        = acc[m][n][rr];
    }

    __threadfence();
    grid.sync();

    // ===================== Phase 5: GRN tail + dense =====================
    {
        int b = bid;
        // split-K reduce: 512 threads, c = tid&255, halves over chunks
        {
            int c = tid & 255, h = tid >> 8;
            float s = 0.f;
            const float* Pp = a.partial + (size_t)b * 256 + c;
            #pragma unroll 8
            for (int ch = h; ch < NCH; ch += 2) s += Pp[(size_t)ch * CHUNK];
            sm.p5.rtmp[h][c] = s;
        }
        __syncthreads();
        if (tid < 256) {
            float rsum = sm.p5.rtmp[0][tid] + sm.p5.rtmp[1][tid];
            if (tid < 128) {
                float hp = rsum + a.b2[tid];
                sm.p5.hs[tid] = hp > 0.f ? hp : expm1f(hp);
            } else {
                sm.p5.ss[tid - 128] = rsum + a.bs[tid - 128];
            }
        }
        __syncthreads();

        int c = tid & 127;
        {   // h2 = h1 @ W1 + b1, k split in 4 quarters
            int qt = tid >> 7;
            float s = 0.f;
            int kb = qt * 32;
            #pragma unroll 8
            for (int k = 0; k < 32; ++k) s += sm.p5.hs[kb + k] * a.W1[(size_t)(kb + k) * 128 + c];
            sm.p5.red4[qt][c] = s;
        }
        __syncthreads();
        if (tid < 128)
            sm.p5.h2s[tid] = sm.p5.red4[0][tid] + sm.p5.red4[1][tid]
                           + sm.p5.red4[2][tid] + sm.p5.red4[3][tid] + a.b1[tid];
        __syncthreads();
        {   // gate / value, k split in halves: idx = kh*2 + sel
            int idx = tid >> 7, sel = idx & 1, kh = idx >> 1;
            const float* Wx = sel ? a.Wv : a.Wg;
            float s = 0.f;
            int kb = kh * 64;
            #pragma unroll 8
            for (int k = 0; k < 64; ++k) s += sm.p5.h2s[kb + k] * Wx[(size_t)(kb + k) * 128 + c];
            sm.p5.red4[idx][c] = s;
        }
        __syncthreads();
        if (tid < 128) {
            float g = 1.f / (1.f + expf(-(sm.p5.red4[0][c] + sm.p5.red4[2][c] + a.bg[c])));
            float v = sm.p5.red4[1][c] + sm.p5.red4[3][c] + a.bv[c];
            sm.p5.ys[c] = sm.p5.ss[c] + g * v;
        }
        __syncthreads();
        if (tid < 128) {
            float sum = 0.f, sq = 0.f;
            for (int k = 0; k < 128; ++k) { float v = sm.p5.ys[k]; sum += v; sq += v * v; }
            float mu = sum * (1.f / 128.f);
            float var = sq * (1.f / 128.f) - mu * mu;
            float rs = rsqrtf(var + LN_EPS);
            float yn = (sm.p5.ys[c] - mu) * rs * a.gamma[c] + a.beta[c];
            sm.p5.es[c] = yn;
        }
        __syncthreads();
        if (tid < 128) {
            float m = -1e30f;
            for (int k = 0; k < 128; ++k) m = fmaxf(m, sm.p5.es[k]);
            float e = expf(sm.p5.es[c] - m);
            sm.p5.ys[c] = e;
        }
        __syncthreads();
        if (tid < 128) {
            float se = 0.f;
            for (int k = 0; k < 128; ++k) se += sm.p5.ys[k];
            sm.p5.wts[c] = sm.p5.ys[c] / se;
        }
        __syncthreads();

        // dense: out[t][d] = (sum_k xbf[t][k] WdTg[d][k] + bd[d]) * wts[d]
        // 8 waves: wave w4 covers cols [w4*16, +16), rows 0..63 (4 m-frags)
        int w4 = tid >> 6;
        const unsigned short* xrow = a.xbf + (size_t)b * 8192;
        f32x4 dacc[4];
        #pragma unroll
        for (int fm = 0; fm < 4; ++fm) dacc[fm] = (f32x4){0.f, 0.f, 0.f, 0.f};
        #pragma unroll
        for (int ks = 0; ks < 4; ++ks) {
            bf16x8 av[4], bv2;
            #pragma unroll
            for (int fm = 0; fm < 4; ++fm)
                av[fm] = *(const bf16x8*)(xrow + (size_t)(fm * 16 + l15) * 128 + ks * 32 + lg * 8);
            bv2 = *(const bf16x8*)(a.WdTg + (size_t)(w4 * 16 + l15) * 128 + ks * 32 + lg * 8);
            #pragma unroll
            for (int fm = 0; fm < 4; ++fm)
                dacc[fm] = __builtin_amdgcn_mfma_f32_16x16x32_bf16(av[fm], bv2, dacc[fm], 0, 0, 0);
        }
        int dcol = w4 * 16 + l15;
        float bdv = a.bd[dcol], wtv = sm.p5.wts[dcol];
        #pragma unroll
        for (int fm = 0; fm < 4; ++fm)
            #pragma unroll
            for (int rr = 0; rr < 4; ++rr) {
                int t = fm * 16 + lg * 4 + rr;
                a.out[(size_t)b * 8192 + (size_t)t * 128 + dcol] = (dacc[fm][rr] + bdv) * wtv;
            }
    }
}

// ---------------------------------------------------------------------------
extern "C" void kernel_launch(void* const* d_in, const int* in_sizes, int n_in,
                              void* d_out, int out_size, void* d_ws, size_t ws_size,
                              hipStream_t stream) {
    char* ws = (char*)d_ws;
    Args a;
    a.x     = (const float*)d_in[0];
    a.tk    = (const float*)d_in[1];
    a.Wd    = (const float*)d_in[2];
    a.bd    = (const float*)d_in[3];
    a.W2    = (const float*)d_in[4];
    a.b2    = (const float*)d_in[5];
    a.W1    = (const float*)d_in[6];
    a.b1    = (const float*)d_in[7];
    a.Wg    = (const float*)d_in[8];
    a.bg    = (const float*)d_in[9];
    a.Wv    = (const float*)d_in[10];
    a.bv    = (const float*)d_in[11];
    a.Wsk   = (const float*)d_in[12];
    a.bs    = (const float*)d_in[13];
    a.gamma = (const float*)d_in[14];
    a.beta  = (const float*)d_in[15];
    a.out   = (float*)d_out;
    a.sig     = (unsigned short*)ws;                       //  8,454,144 B
    a.partial = (float*)(ws + 8454144);                    // 16,777,216 B
    a.xbf     = (unsigned short*)(ws + 8454144 + 16777216);//  4,194,304 B
    a.WdTg    = (unsigned short*)(ws + 8454144 + 16777216 + 4194304); // 32,768 B

    void* kargs[] = { (void*)&a };
    hipLaunchCooperativeKernel((void*)k_fused, dim3(256), dim3(512), kargs, 0, stream);
}

// Round 6
// 47.686 us; speedup vs baseline: 5.1974x; 5.1974x over previous
//
#include <hip/hip_runtime.h>
#include <math.h>

#define SD 16512            // 128 + 128*128
#define NCH 129             // K-chunks (KCH=128)
#define CHUNK 65536         // per-chunk partial elements (256*256)
#define LN_EPS 1e-5f

typedef __attribute__((ext_vector_type(4))) float f32x4;
typedef __attribute__((ext_vector_type(8))) short bf16x8;

__device__ __forceinline__ unsigned bfpack(float lo, float hi) {
    unsigned a = __builtin_bit_cast(unsigned, lo);
    unsigned b = __builtin_bit_cast(unsigned, hi);
    a = (a + 0x7FFFu + ((a >> 16) & 1u)) >> 16;
    b = (b + 0x7FFFu + ((b >> 16) & 1u)) >> 16;
    return a | (b << 16);
}
__device__ __forceinline__ unsigned short bf1(float x) {
    unsigned a = __builtin_bit_cast(unsigned, x);
    return (unsigned short)((a + 0x7FFFu + ((a >> 16) & 1u)) >> 16);
}

// ---------------------------------------------------------------------------
// K1: signature via MFMA. grid 257: blocks 0..255 = batch; block 256 = Wd prep.
// sig[b] = [S1(128) | S2(128x128 row-major)] bf16.
// Also writes xbf[b][t][d] = bf16(tk[t]*x[b][t][d]) and (block 256) WdTg[d][k].
// ---------------------------------------------------------------------------
__global__ __launch_bounds__(256) void k_sig(const float* __restrict__ x,
                                             const float* __restrict__ tk,
                                             const float* __restrict__ Wd,
                                             unsigned short* __restrict__ sig,
                                             unsigned short* __restrict__ xbf,
                                             unsigned short* __restrict__ WdTg) {
    __shared__ unsigned short Ut[128][72];
    __shared__ unsigned short DXt[128][72];
    __shared__ float tks[64];
    int tid = threadIdx.x;
    int b = blockIdx.x;

    if (b == 256) {
        int d = tid & 127, kh = tid >> 7;
        unsigned* dst = (unsigned*)WdTg;
        for (int kk = 0; kk < 64; kk += 2) {
            int k = kh * 64 + kk;
            float v0 = Wd[(size_t)k * 128 + d];
            float v1 = Wd[(size_t)(k + 1) * 128 + d];
            dst[d * 64 + ((kh * 64 + kk) >> 1)] = bfpack(v0, v1);
        }
        return;
    }

    if (tid < 64) tks[tid] = tk[tid];
    __syncthreads();

    const float* xb = x + (size_t)b * 8192;
    unsigned short* xbb = xbf + (size_t)b * 8192;
    int i = tid & 127, th = tid >> 7;

    float x0 = tks[0] * xb[i];
    float xa = tks[th * 32] * xb[(size_t)(th * 32) * 128 + i];
    for (int tp = 0; tp < 16; ++tp) {
        int p = th * 16 + tp;
        int t0 = 2 * p;
        float xv = tks[t0 + 1] * xb[(size_t)(t0 + 1) * 128 + i];
        float dx0 = xv - xa, u0 = 0.5f * (xa + xv) - x0;
        float dx1, u1, xc;
        if (p == 31) { dx1 = 0.f; u1 = 0.f; xc = 0.f; }
        else {
            xc = tks[t0 + 2] * xb[(size_t)(t0 + 2) * 128 + i];
            dx1 = xc - xv; u1 = 0.5f * (xv + xc) - x0;
        }
        *(unsigned*)&Ut[i][t0]  = bfpack(u0, u1);
        *(unsigned*)&DXt[i][t0] = bfpack(dx0, dx1);
        xbb[(size_t)t0 * 128 + i]       = bf1(xa);
        xbb[(size_t)(t0 + 1) * 128 + i] = bf1(xv);
        if (p == 31) sig[(size_t)b * SD + i] = bf1(xv - x0);   // S1
        xa = xc;
    }
    __syncthreads();

    int w = tid >> 6, lane = tid & 63;
    int wm = w >> 1, wn = w & 1;
    int l15 = lane & 15, lg = lane >> 4;
    f32x4 acc[4][4];
    #pragma unroll
    for (int m = 0; m < 4; ++m)
        #pragma unroll
        for (int n = 0; n < 4; ++n) acc[m][n] = (f32x4){0.f, 0.f, 0.f, 0.f};

    #pragma unroll
    for (int ks = 0; ks < 2; ++ks) {
        bf16x8 af[4], bfv[4];
        #pragma unroll
        for (int m = 0; m < 4; ++m)
            af[m] = *(const bf16x8*)&Ut[wm * 64 + m * 16 + l15][ks * 32 + lg * 8];
        #pragma unroll
        for (int n = 0; n < 4; ++n)
            bfv[n] = *(const bf16x8*)&DXt[wn * 64 + n * 16 + l15][ks * 32 + lg * 8];
        #pragma unroll
        for (int m = 0; m < 4; ++m)
            #pragma unroll
            for (int n = 0; n < 4; ++n)
                acc[m][n] = __builtin_amdgcn_mfma_f32_16x16x32_bf16(af[m], bfv[n], acc[m][n], 0, 0, 0);
    }

    unsigned short* sp = sig + (size_t)b * SD + 128;
    #pragma unroll
    for (int m = 0; m < 4; ++m)
        #pragma unroll
        for (int n = 0; n < 4; ++n)
            #pragma unroll
            for (int rr = 0; rr < 4; ++rr)
                sp[(size_t)(wm * 64 + m * 16 + lg * 4 + rr) * 128 + wn * 64 + n * 16 + l15]
                    = bf1(acc[m][n][rr]);
}

// ---------------------------------------------------------------------------
// K2: split-K GEMM, one chunk of K=128 per block group. grid 516 = 129 ch x
// 4 nt (64-col tiles: nt<2 -> W2, else Ws). 512 thr = 8 waves, each wave 32
// rows x 64 cols. A-chunk (64KB) + B-slice (16KB) staged to LDS ONCE
// (XOR-swizzled), one barrier, 4 pure MFMA steps. 2 blocks/CU.
// ---------------------------------------------------------------------------
__global__ __launch_bounds__(512, 2) void k_gemm(const unsigned short* __restrict__ sig,
                                                 const float* __restrict__ W2,
                                                 const float* __restrict__ Ws,
                                                 float* __restrict__ partial) {
    __shared__ unsigned short As[256 * 128];   // 64 KB, swizzled
    __shared__ unsigned short Bs[64 * 128];    // 16 KB, swizzled (B^T: [col][k])

    // bijective XCD swizzle, nwg=516: q=64, r=4 -> 4 nt-siblings same XCD
    int p = blockIdx.x;
    int xc = p & 7, o = p >> 3;
    int lid = (xc < 4 ? xc * 65 : 260 + (xc - 4) * 64) + o;
    int ch = lid >> 2, nt = lid & 3;
    const float* W = (nt < 2) ? W2 : Ws;
    int ntc = (nt & 1) * 64;
    int kb = ch * 128;

    int tid = threadIdx.x;

    // ---- A stage: 256 rows x 128 k bf16; thread: row=tid>>1, half=tid&1,
    //      8 x uint4 (64 bf16) per thread ----
    {
        int row = tid >> 1, half = tid & 1;
        const unsigned short* src = sig + (size_t)row * SD + kb + half * 64;
        int sw = (row & 7) << 3;
        #pragma unroll
        for (int j = 0; j < 8; ++j) {
            uint4 v = *(const uint4*)(src + j * 8);
            int cu = (half * 64 + j * 8) ^ sw;
            *(uint4*)&As[row * 128 + cu] = v;
        }
    }
    // ---- B stage: W[kb..kb+127][ntc..ntc+63] f32 -> Bs[col][k] bf16 ----
    {
        int k = tid >> 2, cq = (tid & 3) * 16;
        const float* wp = W + (size_t)(kb + k) * 128 + ntc + cq;
        float v[16];
        #pragma unroll
        for (int u = 0; u < 4; ++u) {
            f32x4 t = *(const f32x4*)(wp + u * 4);
            v[u * 4] = t[0]; v[u * 4 + 1] = t[1]; v[u * 4 + 2] = t[2]; v[u * 4 + 3] = t[3];
        }
        #pragma unroll
        for (int u = 0; u < 16; ++u) {
            int c = cq + u;
            Bs[c * 128 + (k ^ ((c & 7) << 3))] = bf1(v[u]);
        }
    }
    __syncthreads();

    // ---- compute: wave w -> rows [w*32, +32), all 64 cols ----
    int w = tid >> 6, lane = tid & 63;
    int l15 = lane & 15, lg = lane >> 4;
    int rbase = w * 32;

    f32x4 acc[2][4];
    #pragma unroll
    for (int m = 0; m < 2; ++m)
        #pragma unroll
        for (int n = 0; n < 4; ++n) acc[m][n] = (f32x4){0.f, 0.f, 0.f, 0.f};

    #pragma unroll
    for (int ks = 0; ks < 4; ++ks) {
        bf16x8 af[2], bfv[4];
        #pragma unroll
        for (int m = 0; m < 2; ++m) {
            int row = rbase + m * 16 + l15;
            af[m] = *(const bf16x8*)&As[row * 128 + ((ks * 32 + lg * 8) ^ ((row & 7) << 3))];
        }
        #pragma unroll
        for (int n = 0; n < 4; ++n) {
            int col = n * 16 + l15;
            bfv[n] = *(const bf16x8*)&Bs[col * 128 + ((ks * 32 + lg * 8) ^ ((col & 7) << 3))];
        }
        #pragma unroll
        for (int m = 0; m < 2; ++m)
            #pragma unroll
            for (int n = 0; n < 4; ++n)
                acc[m][n] = __builtin_amdgcn_mfma_f32_16x16x32_bf16(af[m], bfv[n], acc[m][n], 0, 0, 0);
    }

    float* Pp = partial + (size_t)ch * CHUNK + nt * 64;
    #pragma unroll
    for (int m = 0; m < 2; ++m)
        #pragma unroll
        for (int n = 0; n < 4; ++n)
            #pragma unroll
            for (int rr = 0; rr < 4; ++rr)
                Pp[(size_t)(rbase + m * 16 + lg * 4 + rr) * 256 + n * 16 + l15]
                    = acc[m][n][rr];
}

// ---------------------------------------------------------------------------
// K3: fused tail. Reduce partials + GRN + LN + softmax (LDS) + dense MFMA.
// grid 256 (batch), block 512.
// ---------------------------------------------------------------------------
__global__ __launch_bounds__(512) void k_tail(const float* __restrict__ partial,
                                              const unsigned short* __restrict__ xbf,
                                              const unsigned short* __restrict__ WdTg,
                                              const float* __restrict__ b2,
                                              const float* __restrict__ W1,
                                              const float* __restrict__ b1,
                                              const float* __restrict__ Wg,
                                              const float* __restrict__ bg,
                                              const float* __restrict__ Wv,
                                              const float* __restrict__ bv,
                                              const float* __restrict__ bs,
                                              const float* __restrict__ gamma,
                                              const float* __restrict__ beta,
                                              const float* __restrict__ bd,
                                              float* __restrict__ out) {
    __shared__ float hs[128], ss[128], h2s[128];
    __shared__ float red4[4][128], rtmp[2][256];
    __shared__ float ys[128], es[128], wts[128];

    int b = blockIdx.x, tid = threadIdx.x;
    int lane = tid & 63;
    int l15 = lane & 15, lg = lane >> 4;

    {   // split-K reduce over 129 chunks, 2-way over threads
        int c = tid & 255, h = tid >> 8;
        float s = 0.f;
        const float* Pp = partial + (size_t)b * 256 + c;
        #pragma unroll 8
        for (int ch = h; ch < NCH; ch += 2) s += Pp[(size_t)ch * CHUNK];
        rtmp[h][c] = s;
    }
    __syncthreads();
    if (tid < 256) {
        float rsum = rtmp[0][tid] + rtmp[1][tid];
        if (tid < 128) {
            float hp = rsum + b2[tid];
            hs[tid] = hp > 0.f ? hp : expm1f(hp);
        } else {
            ss[tid - 128] = rsum + bs[tid - 128];
        }
    }
    __syncthreads();

    int c = tid & 127;
    {   // h2 = h1 @ W1 + b1, k split in 4 quarters
        int qt = tid >> 7;
        float s = 0.f;
        int kbq = qt * 32;
        #pragma unroll 8
        for (int k = 0; k < 32; ++k) s += hs[kbq + k] * W1[(size_t)(kbq + k) * 128 + c];
        red4[qt][c] = s;
    }
    __syncthreads();
    if (tid < 128)
        h2s[tid] = red4[0][tid] + red4[1][tid] + red4[2][tid] + red4[3][tid] + b1[tid];
    __syncthreads();
    {   // gate / value, k split in halves
        int idx = tid >> 7, sel = idx & 1, kh = idx >> 1;
        const float* Wx = sel ? Wv : Wg;
        float s = 0.f;
        int kbq = kh * 64;
        #pragma unroll 8
        for (int k = 0; k < 64; ++k) s += h2s[kbq + k] * Wx[(size_t)(kbq + k) * 128 + c];
        red4[idx][c] = s;
    }
    __syncthreads();
    if (tid < 128) {
        float g = 1.f / (1.f + expf(-(red4[0][c] + red4[2][c] + bg[c])));
        float v = red4[1][c] + red4[3][c] + bv[c];
        ys[c] = ss[c] + g * v;
    }
    __syncthreads();
    if (tid < 128) {
        float sum = 0.f, sq = 0.f;
        for (int k = 0; k < 128; ++k) { float v = ys[k]; sum += v; sq += v * v; }
        float mu = sum * (1.f / 128.f);
        float var = sq * (1.f / 128.f) - mu * mu;
        float rs = rsqrtf(var + LN_EPS);
        es[c] = (ys[c] - mu) * rs * gamma[c] + beta[c];
    }
    __syncthreads();
    if (tid < 128) {
        float m = -1e30f;
        for (int k = 0; k < 128; ++k) m = fmaxf(m, es[k]);
        ys[c] = expf(es[c] - m);
    }
    __syncthreads();
    if (tid < 128) {
        float se = 0.f;
        for (int k = 0; k < 128; ++k) se += ys[k];
        wts[c] = ys[c] / se;
    }
    __syncthreads();

    // dense: out[t][d] = (sum_k xbf[t][k] WdTg[d][k] + bd[d]) * wts[d]
    int w4 = tid >> 6;
    const unsigned short* xrow = xbf + (size_t)b * 8192;
    f32x4 dacc[4];
    #pragma unroll
    for (int fm = 0; fm < 4; ++fm) dacc[fm] = (f32x4){0.f, 0.f, 0.f, 0.f};
    #pragma unroll
    for (int ks = 0; ks < 4; ++ks) {
        bf16x8 av[4], bv2;
        #pragma unroll
        for (int fm = 0; fm < 4; ++fm)
            av[fm] = *(const bf16x8*)(xrow + (size_t)(fm * 16 + l15) * 128 + ks * 32 + lg * 8);
        bv2 = *(const bf16x8*)(WdTg + (size_t)(w4 * 16 + l15) * 128 + ks * 32 + lg * 8);
        #pragma unroll
        for (int fm = 0; fm < 4; ++fm)
            dacc[fm] = __builtin_amdgcn_mfma_f32_16x16x32_bf16(av[fm], bv2, dacc[fm], 0, 0, 0);
    }
    int dcol = w4 * 16 + l15;
    float bdv = bd[dcol], wtv = wts[dcol];
    #pragma unroll
    for (int fm = 0; fm < 4; ++fm)
        #pragma unroll
        for (int rr = 0; rr < 4; ++rr) {
            int t = fm * 16 + lg * 4 + rr;
            out[(size_t)b * 8192 + (size_t)t * 128 + dcol] = (dacc[fm][rr] + bdv) * wtv;
        }
}

// ---------------------------------------------------------------------------
extern "C" void kernel_launch(void* const* d_in, const int* in_sizes, int n_in,
                              void* d_out, int out_size, void* d_ws, size_t ws_size,
                              hipStream_t stream) {
    const float* inputs = (const float*)d_in[0];
    const float* tk     = (const float*)d_in[1];
    const float* Wd     = (const float*)d_in[2];
    const float* bd     = (const float*)d_in[3];
    const float* W2     = (const float*)d_in[4];
    const float* b2     = (const float*)d_in[5];
    const float* W1     = (const float*)d_in[6];
    const float* b1     = (const float*)d_in[7];
    const float* Wg     = (const float*)d_in[8];
    const float* bg     = (const float*)d_in[9];
    const float* Wv     = (const float*)d_in[10];
    const float* bv     = (const float*)d_in[11];
    const float* Wsk    = (const float*)d_in[12];
    const float* bs     = (const float*)d_in[13];
    const float* gamma  = (const float*)d_in[14];
    const float* beta   = (const float*)d_in[15];
    float* out = (float*)d_out;

    char* ws = (char*)d_ws;
    unsigned short* sig  = (unsigned short*)ws;                 //  8,454,144 B
    float* partial       = (float*)(ws + 8454144);              // 33,816,576 B
    unsigned short* xbf  = (unsigned short*)(ws + 42270720);    //  4,194,304 B
    unsigned short* WdTg = (unsigned short*)(ws + 46465024);    //     32,768 B

    k_sig <<<257, 256, 0, stream>>>(inputs, tk, Wd, sig, xbf, WdTg);
    k_gemm<<<516, 512, 0, stream>>>(sig, W2, Wsk, partial);
    k_tail<<<256, 512, 0, stream>>>(partial, xbf, WdTg, b2, W1, b1, Wg, bg, Wv, bv,
                                    bs, gamma, beta, bd, out);
}

// Round 7
// 44.577 us; speedup vs baseline: 5.5599x; 1.0698x over previous
//
#include <hip/hip_runtime.h>
#include <math.h>

#define SD 16512            // 128 + 128*128
#define NCH 129             // K-chunks (KCH=128)
#define CHUNKP 32768        // per-chunk packed partial (128 row-pairs x 256 cols)
#define LN_EPS 1e-5f

typedef __attribute__((ext_vector_type(4))) float f32x4;
typedef __attribute__((ext_vector_type(8))) short bf16x8;

__device__ __forceinline__ unsigned bfpack(float lo, float hi) {
    unsigned a = __builtin_bit_cast(unsigned, lo);
    unsigned b = __builtin_bit_cast(unsigned, hi);
    a = (a + 0x7FFFu + ((a >> 16) & 1u)) >> 16;
    b = (b + 0x7FFFu + ((b >> 16) & 1u)) >> 16;
    return a | (b << 16);
}
__device__ __forceinline__ unsigned short bf1(float x) {
    unsigned a = __builtin_bit_cast(unsigned, x);
    return (unsigned short)((a + 0x7FFFu + ((a >> 16) & 1u)) >> 16);
}

// ---------------------------------------------------------------------------
// K1: signature via MFMA. grid 257 x 512: blocks 0..255 = batch; 256 = Wd prep.
// sig[b] = [S1(128) | S2(128x128 row-major)] bf16.
// Also writes xbf[b][t][d] = bf16(tk[t]*x[b][t][d]) and (block 256) WdTg[d][k].
// 512 thr: i = tid&127, th = tid>>7 (4-way time split, 8 serial pairs each).
// ---------------------------------------------------------------------------
__global__ __launch_bounds__(512) void k_sig(const float* __restrict__ x,
                                             const float* __restrict__ tk,
                                             const float* __restrict__ Wd,
                                             unsigned short* __restrict__ sig,
                                             unsigned short* __restrict__ xbf,
                                             unsigned short* __restrict__ WdTg) {
    __shared__ unsigned short Ut[128][72];
    __shared__ unsigned short DXt[128][72];
    __shared__ float tks[64];
    int tid = threadIdx.x;
    int b = blockIdx.x;

    if (b == 256) {
        int d = tid & 127, kh = tid >> 7;          // kh 0..3, 32 k each
        unsigned* dst = (unsigned*)WdTg;
        for (int kk = 0; kk < 32; kk += 2) {
            int k = kh * 32 + kk;
            float v0 = Wd[(size_t)k * 128 + d];
            float v1 = Wd[(size_t)(k + 1) * 128 + d];
            dst[d * 64 + (k >> 1)] = bfpack(v0, v1);
        }
        return;
    }

    if (tid < 64) tks[tid] = tk[tid];
    __syncthreads();

    const float* xb = x + (size_t)b * 8192;
    unsigned short* xbb = xbf + (size_t)b * 8192;
    int i = tid & 127, th = tid >> 7;              // th 0..3, 8 pairs each

    float x0 = tks[0] * xb[i];
    float xa = tks[th * 16] * xb[(size_t)(th * 16) * 128 + i];
    #pragma unroll
    for (int tp = 0; tp < 8; ++tp) {
        int p = th * 8 + tp;
        int t0 = 2 * p;
        float xv = tks[t0 + 1] * xb[(size_t)(t0 + 1) * 128 + i];
        float dx0 = xv - xa, u0 = 0.5f * (xa + xv) - x0;
        float dx1, u1, xc;
        if (p == 31) { dx1 = 0.f; u1 = 0.f; xc = 0.f; }
        else {
            xc = tks[t0 + 2] * xb[(size_t)(t0 + 2) * 128 + i];
            dx1 = xc - xv; u1 = 0.5f * (xv + xc) - x0;
        }
        *(unsigned*)&Ut[i][t0]  = bfpack(u0, u1);
        *(unsigned*)&DXt[i][t0] = bfpack(dx0, dx1);
        xbb[(size_t)t0 * 128 + i]       = bf1(xa);
        xbb[(size_t)(t0 + 1) * 128 + i] = bf1(xv);
        if (p == 31) sig[(size_t)b * SD + i] = bf1(xv - x0);   // S1
        xa = xc;
    }
    __syncthreads();

    // S2 = Ut(128 x 64k) @ DXt^T. 8 waves: 2M x 4N, wave tile 64x32.
    int w = tid >> 6, lane = tid & 63;
    int wm = w >> 2, wn = w & 3;
    int l15 = lane & 15, lg = lane >> 4;
    f32x4 acc[4][2];
    #pragma unroll
    for (int m = 0; m < 4; ++m)
        #pragma unroll
        for (int n = 0; n < 2; ++n) acc[m][n] = (f32x4){0.f, 0.f, 0.f, 0.f};

    #pragma unroll
    for (int ks = 0; ks < 2; ++ks) {
        bf16x8 af[4], bfv[2];
        #pragma unroll
        for (int m = 0; m < 4; ++m)
            af[m] = *(const bf16x8*)&Ut[wm * 64 + m * 16 + l15][ks * 32 + lg * 8];
        #pragma unroll
        for (int n = 0; n < 2; ++n)
            bfv[n] = *(const bf16x8*)&DXt[wn * 32 + n * 16 + l15][ks * 32 + lg * 8];
        #pragma unroll
        for (int m = 0; m < 4; ++m)
            #pragma unroll
            for (int n = 0; n < 2; ++n)
                acc[m][n] = __builtin_amdgcn_mfma_f32_16x16x32_bf16(af[m], bfv[n], acc[m][n], 0, 0, 0);
    }

    unsigned short* sp = sig + (size_t)b * SD + 128;
    #pragma unroll
    for (int m = 0; m < 4; ++m)
        #pragma unroll
        for (int n = 0; n < 2; ++n)
            #pragma unroll
            for (int rr = 0; rr < 4; ++rr)
                sp[(size_t)(wm * 64 + m * 16 + lg * 4 + rr) * 128 + wn * 32 + n * 16 + l15]
                    = bf1(acc[m][n][rr]);
}

// ---------------------------------------------------------------------------
// K2: split-K GEMM, grid 516 = 129 ch x 4 nt (64-col tiles; nt<2 -> W2 else Ws).
// 512 thr = 8 waves, wave = 32 rows x 64 cols. A (64KB) + B (16KB) staged to
// LDS once (XOR-swizzled), 1 barrier, 4 pure MFMA steps. Partial packed bf16:
// row-pairs in u32 -> partial_p[ch][128][256].
// ---------------------------------------------------------------------------
__global__ __launch_bounds__(512, 2) void k_gemm(const unsigned short* __restrict__ sig,
                                                 const float* __restrict__ W2,
                                                 const float* __restrict__ Ws,
                                                 unsigned* __restrict__ partial_p) {
    __shared__ unsigned short As[256 * 128];   // 64 KB, swizzled
    __shared__ unsigned short Bs[64 * 128];    // 16 KB, swizzled (B^T: [col][k])

    // bijective XCD swizzle, nwg=516: q=64, r=4 -> 4 nt-siblings same XCD
    int p = blockIdx.x;
    int xc = p & 7, o = p >> 3;
    int lid = (xc < 4 ? xc * 65 : 260 + (xc - 4) * 64) + o;
    int ch = lid >> 2, nt = lid & 3;
    const float* W = (nt < 2) ? W2 : Ws;
    int ntc = (nt & 1) * 64;
    int kb = ch * 128;

    int tid = threadIdx.x;

    // ---- A stage: 256 rows x 128 k bf16; 8 x uint4 per thread ----
    {
        int row = tid >> 1, half = tid & 1;
        const unsigned short* src = sig + (size_t)row * SD + kb + half * 64;
        int sw = (row & 7) << 3;
        #pragma unroll
        for (int j = 0; j < 8; ++j) {
            uint4 v = *(const uint4*)(src + j * 8);
            int cu = (half * 64 + j * 8) ^ sw;
            *(uint4*)&As[row * 128 + cu] = v;
        }
    }
    // ---- B stage: W[kb..kb+127][ntc..ntc+63] f32 -> Bs[col][k] bf16 ----
    {
        int k = tid >> 2, cq = (tid & 3) * 16;
        const float* wp = W + (size_t)(kb + k) * 128 + ntc + cq;
        float v[16];
        #pragma unroll
        for (int u = 0; u < 4; ++u) {
            f32x4 t = *(const f32x4*)(wp + u * 4);
            v[u * 4] = t[0]; v[u * 4 + 1] = t[1]; v[u * 4 + 2] = t[2]; v[u * 4 + 3] = t[3];
        }
        #pragma unroll
        for (int u = 0; u < 16; ++u) {
            int c = cq + u;
            Bs[c * 128 + (k ^ ((c & 7) << 3))] = bf1(v[u]);
        }
    }
    __syncthreads();

    // ---- compute: wave w -> rows [w*32, +32), all 64 cols ----
    int w = tid >> 6, lane = tid & 63;
    int l15 = lane & 15, lg = lane >> 4;
    int rbase = w * 32;

    f32x4 acc[2][4];
    #pragma unroll
    for (int m = 0; m < 2; ++m)
        #pragma unroll
        for (int n = 0; n < 4; ++n) acc[m][n] = (f32x4){0.f, 0.f, 0.f, 0.f};

    #pragma unroll
    for (int ks = 0; ks < 4; ++ks) {
        bf16x8 af[2], bfv[4];
        #pragma unroll
        for (int m = 0; m < 2; ++m) {
            int row = rbase + m * 16 + l15;
            af[m] = *(const bf16x8*)&As[row * 128 + ((ks * 32 + lg * 8) ^ ((row & 7) << 3))];
        }
        #pragma unroll
        for (int n = 0; n < 4; ++n) {
            int col = n * 16 + l15;
            bfv[n] = *(const bf16x8*)&Bs[col * 128 + ((ks * 32 + lg * 8) ^ ((col & 7) << 3))];
        }
        #pragma unroll
        for (int m = 0; m < 2; ++m)
            #pragma unroll
            for (int n = 0; n < 4; ++n)
                acc[m][n] = __builtin_amdgcn_mfma_f32_16x16x32_bf16(af[m], bfv[n], acc[m][n], 0, 0, 0);
    }

    // ---- packed bf16 store: rows r0..r0+3 -> row-pairs r0/2, r0/2+1 ----
    unsigned* Pp = partial_p + (size_t)ch * CHUNKP + nt * 64;
    #pragma unroll
    for (int m = 0; m < 2; ++m)
        #pragma unroll
        for (int n = 0; n < 4; ++n) {
            int r0 = rbase + m * 16 + lg * 4;
            int cc = n * 16 + l15;
            Pp[(size_t)(r0 >> 1) * 256 + cc]       = bfpack(acc[m][n][0], acc[m][n][1]);
            Pp[(size_t)((r0 >> 1) + 1) * 256 + cc] = bfpack(acc[m][n][2], acc[m][n][3]);
        }
}

// ---------------------------------------------------------------------------
// K3: fused tail. Reduce packed partials + GRN + LN + softmax + dense MFMA.
// grid 256 (batch), block 512.
// ---------------------------------------------------------------------------
__global__ __launch_bounds__(512) void k_tail(const unsigned* __restrict__ partial_p,
                                              const unsigned short* __restrict__ xbf,
                                              const unsigned short* __restrict__ WdTg,
                                              const float* __restrict__ b2,
                                              const float* __restrict__ W1,
                                              const float* __restrict__ b1,
                                              const float* __restrict__ Wg,
                                              const float* __restrict__ bg,
                                              const float* __restrict__ Wv,
                                              const float* __restrict__ bv,
                                              const float* __restrict__ bs,
                                              const float* __restrict__ gamma,
                                              const float* __restrict__ beta,
                                              const float* __restrict__ bd,
                                              float* __restrict__ out) {
    __shared__ float hs[128], ss[128], h2s[128];
    __shared__ float red4[4][128], rtmp[2][256];
    __shared__ float ys[128], es[128], wts[128];

    int b = blockIdx.x, tid = threadIdx.x;
    int lane = tid & 63;
    int l15 = lane & 15, lg = lane >> 4;

    {   // split-K reduce over 129 chunks, 2-way over threads; unpack bf16 half
        int c = tid & 255, h = tid >> 8;
        float s = 0.f;
        const unsigned* Pp = partial_p + (size_t)(b >> 1) * 256 + c;
        bool hi = (b & 1) != 0;
        #pragma unroll 8
        for (int ch = h; ch < NCH; ch += 2) {
            unsigned u = Pp[(size_t)ch * CHUNKP];
            unsigned hw = hi ? (u & 0xffff0000u) : (u << 16);
            s += __builtin_bit_cast(float, hw);
        }
        rtmp[h][c] = s;
    }
    __syncthreads();
    if (tid < 256) {
        float rsum = rtmp[0][tid] + rtmp[1][tid];
        if (tid < 128) {
            float hp = rsum + b2[tid];
            hs[tid] = hp > 0.f ? hp : expm1f(hp);
        } else {
            ss[tid - 128] = rsum + bs[tid - 128];
        }
    }
    __syncthreads();

    int c = tid & 127;
    {   // h2 = h1 @ W1 + b1, k split in 4 quarters
        int qt = tid >> 7;
        float s = 0.f;
        int kbq = qt * 32;
        #pragma unroll 8
        for (int k = 0; k < 32; ++k) s += hs[kbq + k] * W1[(size_t)(kbq + k) * 128 + c];
        red4[qt][c] = s;
    }
    __syncthreads();
    if (tid < 128)
        h2s[tid] = red4[0][tid] + red4[1][tid] + red4[2][tid] + red4[3][tid] + b1[tid];
    __syncthreads();
    {   // gate / value, k split in halves
        int idx = tid >> 7, sel = idx & 1, kh = idx >> 1;
        const float* Wx = sel ? Wv : Wg;
        float s = 0.f;
        int kbq = kh * 64;
        #pragma unroll 8
        for (int k = 0; k < 64; ++k) s += h2s[kbq + k] * Wx[(size_t)(kbq + k) * 128 + c];
        red4[idx][c] = s;
    }
    __syncthreads();
    if (tid < 128) {
        float g = 1.f / (1.f + expf(-(red4[0][c] + red4[2][c] + bg[c])));
        float v = red4[1][c] + red4[3][c] + bv[c];
        ys[c] = ss[c] + g * v;
    }
    __syncthreads();
    if (tid < 128) {
        float sum = 0.f, sq = 0.f;
        for (int k = 0; k < 128; ++k) { float v = ys[k]; sum += v; sq += v * v; }
        float mu = sum * (1.f / 128.f);
        float var = sq * (1.f / 128.f) - mu * mu;
        float rs = rsqrtf(var + LN_EPS);
        es[c] = (ys[c] - mu) * rs * gamma[c] + beta[c];
    }
    __syncthreads();
    if (tid < 128) {
        float m = -1e30f;
        for (int k = 0; k < 128; ++k) m = fmaxf(m, es[k]);
        ys[c] = expf(es[c] - m);
    }
    __syncthreads();
    if (tid < 128) {
        float se = 0.f;
        for (int k = 0; k < 128; ++k) se += ys[k];
        wts[c] = ys[c] / se;
    }
    __syncthreads();

    // dense: out[t][d] = (sum_k xbf[t][k] WdTg[d][k] + bd[d]) * wts[d]
    int w4 = tid >> 6;
    const unsigned short* xrow = xbf + (size_t)b * 8192;
    f32x4 dacc[4];
    #pragma unroll
    for (int fm = 0; fm < 4; ++fm) dacc[fm] = (f32x4){0.f, 0.f, 0.f, 0.f};
    #pragma unroll
    for (int ks = 0; ks < 4; ++ks) {
        bf16x8 av[4], bv2;
        #pragma unroll
        for (int fm = 0; fm < 4; ++fm)
            av[fm] = *(const bf16x8*)(xrow + (size_t)(fm * 16 + l15) * 128 + ks * 32 + lg * 8);
        bv2 = *(const bf16x8*)(WdTg + (size_t)(w4 * 16 + l15) * 128 + ks * 32 + lg * 8);
        #pragma unroll
        for (int fm = 0; fm < 4; ++fm)
            dacc[fm] = __builtin_amdgcn_mfma_f32_16x16x32_bf16(av[fm], bv2, dacc[fm], 0, 0, 0);
    }
    int dcol = w4 * 16 + l15;
    float bdv = bd[dcol], wtv = wts[dcol];
    #pragma unroll
    for (int fm = 0; fm < 4; ++fm)
        #pragma unroll
        for (int rr = 0; rr < 4; ++rr) {
            int t = fm * 16 + lg * 4 + rr;
            out[(size_t)b * 8192 + (size_t)t * 128 + dcol] = (dacc[fm][rr] + bdv) * wtv;
        }
}

// ---------------------------------------------------------------------------
extern "C" void kernel_launch(void* const* d_in, const int* in_sizes, int n_in,
                              void* d_out, int out_size, void* d_ws, size_t ws_size,
                              hipStream_t stream) {
    const float* inputs = (const float*)d_in[0];
    const float* tk     = (const float*)d_in[1];
    const float* Wd     = (const float*)d_in[2];
    const float* bd     = (const float*)d_in[3];
    const float* W2     = (const float*)d_in[4];
    const float* b2     = (const float*)d_in[5];
    const float* W1     = (const float*)d_in[6];
    const float* b1     = (const float*)d_in[7];
    const float* Wg     = (const float*)d_in[8];
    const float* bg     = (const float*)d_in[9];
    const float* Wv     = (const float*)d_in[10];
    const float* bv     = (const float*)d_in[11];
    const float* Wsk    = (const float*)d_in[12];
    const float* bs     = (const float*)d_in[13];
    const float* gamma  = (const float*)d_in[14];
    const float* beta   = (const float*)d_in[15];
    float* out = (float*)d_out;

    char* ws = (char*)d_ws;
    unsigned short* sig  = (unsigned short*)ws;                 //  8,454,144 B
    unsigned* partial_p  = (unsigned*)(ws + 8454144);           // 16,908,288 B
    unsigned short* xbf  = (unsigned short*)(ws + 25362432);    //  4,194,304 B
    unsigned short* WdTg = (unsigned short*)(ws + 29556736);    //     32,768 B

    k_sig <<<257, 512, 0, stream>>>(inputs, tk, Wd, sig, xbf, WdTg);
    k_gemm<<<516, 512, 0, stream>>>(sig, W2, Wsk, partial_p);
    k_tail<<<256, 512, 0, stream>>>(partial_p, xbf, WdTg, b2, W1, b1, Wg, bg, Wv, bv,
                                    bs, gamma, beta, bd, out);
}

// Round 8
// 40.239 us; speedup vs baseline: 6.1593x; 1.1078x over previous
//
#include <hip/hip_runtime.h>
#include <math.h>

#define SD 16512            // 128 + 128*128
#define NCH 32              // K-chunks (31 x 512 + 1 x 640)
#define RPSTRIDE 8192       // partial: [rowpair 128][ch 32][col 256] u32
#define LN_EPS 1e-5f

typedef __attribute__((ext_vector_type(4))) float f32x4;
typedef __attribute__((ext_vector_type(8))) short bf16x8;

__device__ __forceinline__ unsigned bfpack(float lo, float hi) {
    unsigned a = __builtin_bit_cast(unsigned, lo);
    unsigned b = __builtin_bit_cast(unsigned, hi);
    a = (a + 0x7FFFu + ((a >> 16) & 1u)) >> 16;
    b = (b + 0x7FFFu + ((b >> 16) & 1u)) >> 16;
    return a | (b << 16);
}
__device__ __forceinline__ unsigned short bf1(float x) {
    unsigned a = __builtin_bit_cast(unsigned, x);
    return (unsigned short)((a + 0x7FFFu + ((a >> 16) & 1u)) >> 16);
}

// ---------------------------------------------------------------------------
// K1: signature via MFMA. grid 257 x 512: blocks 0..255 = batch; 256 = Wd prep.
// sig[b] = [S1(128) | S2(128x128 row-major)] bf16; xbf = bf16 time-weighted x;
// WdTg[d][k] = bf16(Wd[k][d]).
// ---------------------------------------------------------------------------
__global__ __launch_bounds__(512) void k_sig(const float* __restrict__ x,
                                             const float* __restrict__ tk,
                                             const float* __restrict__ Wd,
                                             unsigned short* __restrict__ sig,
                                             unsigned short* __restrict__ xbf,
                                             unsigned short* __restrict__ WdTg) {
    __shared__ unsigned short Ut[128][72];
    __shared__ unsigned short DXt[128][72];
    __shared__ float tks[64];
    int tid = threadIdx.x;
    int b = blockIdx.x;

    if (b == 256) {
        int d = tid & 127, kh = tid >> 7;          // kh 0..3, 32 k each
        unsigned* dst = (unsigned*)WdTg;
        for (int kk = 0; kk < 32; kk += 2) {
            int k = kh * 32 + kk;
            float v0 = Wd[(size_t)k * 128 + d];
            float v1 = Wd[(size_t)(k + 1) * 128 + d];
            dst[d * 64 + (k >> 1)] = bfpack(v0, v1);
        }
        return;
    }

    if (tid < 64) tks[tid] = tk[tid];
    __syncthreads();

    const float* xb = x + (size_t)b * 8192;
    unsigned short* xbb = xbf + (size_t)b * 8192;
    int i = tid & 127, th = tid >> 7;              // th 0..3, 8 pairs each

    float x0 = tks[0] * xb[i];
    float xa = tks[th * 16] * xb[(size_t)(th * 16) * 128 + i];
    #pragma unroll
    for (int tp = 0; tp < 8; ++tp) {
        int p = th * 8 + tp;
        int t0 = 2 * p;
        float xv = tks[t0 + 1] * xb[(size_t)(t0 + 1) * 128 + i];
        float dx0 = xv - xa, u0 = 0.5f * (xa + xv) - x0;
        float dx1, u1, xc;
        if (p == 31) { dx1 = 0.f; u1 = 0.f; xc = 0.f; }
        else {
            xc = tks[t0 + 2] * xb[(size_t)(t0 + 2) * 128 + i];
            dx1 = xc - xv; u1 = 0.5f * (xv + xc) - x0;
        }
        *(unsigned*)&Ut[i][t0]  = bfpack(u0, u1);
        *(unsigned*)&DXt[i][t0] = bfpack(dx0, dx1);
        xbb[(size_t)t0 * 128 + i]       = bf1(xa);
        xbb[(size_t)(t0 + 1) * 128 + i] = bf1(xv);
        if (p == 31) sig[(size_t)b * SD + i] = bf1(xv - x0);   // S1
        xa = xc;
    }
    __syncthreads();

    // S2 = Ut(128 x 64k) @ DXt^T. 8 waves: 2M x 4N, wave tile 64x32.
    int w = tid >> 6, lane = tid & 63;
    int wm = w >> 2, wn = w & 3;
    int l15 = lane & 15, lg = lane >> 4;
    f32x4 acc[4][2];
    #pragma unroll
    for (int m = 0; m < 4; ++m)
        #pragma unroll
        for (int n = 0; n < 2; ++n) acc[m][n] = (f32x4){0.f, 0.f, 0.f, 0.f};

    #pragma unroll
    for (int ks = 0; ks < 2; ++ks) {
        bf16x8 af[4], bfv[2];
        #pragma unroll
        for (int m = 0; m < 4; ++m)
            af[m] = *(const bf16x8*)&Ut[wm * 64 + m * 16 + l15][ks * 32 + lg * 8];
        #pragma unroll
        for (int n = 0; n < 2; ++n)
            bfv[n] = *(const bf16x8*)&DXt[wn * 32 + n * 16 + l15][ks * 32 + lg * 8];
        #pragma unroll
        for (int m = 0; m < 4; ++m)
            #pragma unroll
            for (int n = 0; n < 2; ++n)
                acc[m][n] = __builtin_amdgcn_mfma_f32_16x16x32_bf16(af[m], bfv[n], acc[m][n], 0, 0, 0);
    }

    unsigned short* sp = sig + (size_t)b * SD + 128;
    #pragma unroll
    for (int m = 0; m < 4; ++m)
        #pragma unroll
        for (int n = 0; n < 2; ++n)
            #pragma unroll
            for (int rr = 0; rr < 4; ++rr)
                sp[(size_t)(wm * 64 + m * 16 + lg * 4 + rr) * 128 + wn * 32 + n * 16 + l15]
                    = bf1(acc[m][n][rr]);
}

// ---------------------------------------------------------------------------
// K2: split-K GEMM, NCH=32 chunks (K=512; last 640). grid 512 = 32ch x 2mt x
// 8nt, block 512 = 8 waves, 2 blocks/CU, ALL blocks resident. Per block:
// output 128 rows x 32 cols; loop 4-5 sub-stages of K=128, single-buffer LDS
// (A 32KB XOR-swizzled + B 8KB). Partial packed bf16 row-pairs, layout
// [rowpair][ch][col] so k_tail's reduce region is contiguous.
// ---------------------------------------------------------------------------
__global__ __launch_bounds__(512, 2) void k_gemm(const unsigned short* __restrict__ sig,
                                                 const float* __restrict__ W2,
                                                 const float* __restrict__ Ws,
                                                 unsigned* __restrict__ partial_p) {
    __shared__ unsigned short As[128 * 128];   // 32 KB, swizzled
    __shared__ unsigned short Bs[32 * 128];    // 8 KB, swizzled (B^T: [col][k])

    // XCD swizzle, nwg=512 (q=64 exact): chunk's 16 siblings -> same XCD
    int p = blockIdx.x;
    int lid = (p & 7) * 64 + (p >> 3);
    int ch = lid >> 4;
    int mt = (lid >> 3) & 1;
    int nt = lid & 7;
    const float* W = (nt < 4) ? W2 : Ws;
    int ntc = (nt & 3) * 32;                   // col offset within W
    int kb0 = ch * 512;
    int nsub = (ch == 31) ? 5 : 4;

    int tid = threadIdx.x;
    int w = tid >> 6, lane = tid & 63;
    int l15 = lane & 15, lg = lane >> 4;
    const unsigned short* sigB = sig + (size_t)(mt * 128) * SD;

    // staging coords
    int arow = tid >> 2;                       // 0..127
    int aq   = (tid & 3) * 32;                 // k base (4 x uint4)
    int bk   = tid >> 2;                       // 0..127
    int bc0  = (tid & 3) * 8;                  // 8 cols each

    f32x4 acc[2];
    acc[0] = (f32x4){0.f, 0.f, 0.f, 0.f};
    acc[1] = (f32x4){0.f, 0.f, 0.f, 0.f};

    for (int s = 0; s < nsub; ++s) {
        int kb = kb0 + s * 128;
        // A stage: 128 rows x 128 k
        {
            const unsigned short* src = sigB + (size_t)arow * SD + kb + aq;
            int sw = (arow & 7) << 3;
            #pragma unroll
            for (int j = 0; j < 4; ++j) {
                uint4 v = *(const uint4*)(src + j * 8);
                *(uint4*)&As[arow * 128 + ((aq + j * 8) ^ sw)] = v;
            }
        }
        // B stage: W[kb..+128][ntc..+32] f32 -> Bs[col][k] bf16
        {
            const float* wp = W + (size_t)(kb + bk) * 128 + ntc + bc0;
            f32x4 t0 = *(const f32x4*)wp;
            f32x4 t1 = *(const f32x4*)(wp + 4);
            float v[8] = {t0[0], t0[1], t0[2], t0[3], t1[0], t1[1], t1[2], t1[3]};
            #pragma unroll
            for (int u = 0; u < 8; ++u) {
                int c = bc0 + u;
                Bs[c * 128 + (bk ^ ((c & 7) << 3))] = bf1(v[u]);
            }
        }
        __syncthreads();

        // compute: wave w -> rows [w*16, +16), 32 cols, K=128
        #pragma unroll
        for (int ks = 0; ks < 4; ++ks) {
            int ko = ks * 32 + lg * 8;
            bf16x8 af, bfv[2];
            {
                int row = w * 16 + l15;
                af = *(const bf16x8*)&As[row * 128 + (ko ^ ((row & 7) << 3))];
            }
            #pragma unroll
            for (int n = 0; n < 2; ++n) {
                int col = n * 16 + l15;
                bfv[n] = *(const bf16x8*)&Bs[col * 128 + (ko ^ ((col & 7) << 3))];
            }
            acc[0] = __builtin_amdgcn_mfma_f32_16x16x32_bf16(af, bfv[0], acc[0], 0, 0, 0);
            acc[1] = __builtin_amdgcn_mfma_f32_16x16x32_bf16(af, bfv[1], acc[1], 0, 0, 0);
        }
        __syncthreads();
    }

    // packed bf16 store: rows r0..r0+3 -> rowpairs; layout [rp][ch][col]
    int r0 = mt * 128 + w * 16 + lg * 4;
    int rp0 = r0 >> 1;
    #pragma unroll
    for (int n = 0; n < 2; ++n) {
        int colg = nt * 32 + n * 16 + l15;
        partial_p[(size_t)rp0 * RPSTRIDE + ch * 256 + colg]
            = bfpack(acc[n][0], acc[n][1]);
        partial_p[(size_t)(rp0 + 1) * RPSTRIDE + ch * 256 + colg]
            = bfpack(acc[n][2], acc[n][3]);
    }
}

// ---------------------------------------------------------------------------
// K3: fused tail. Reduce packed partials (contiguous 32KB span per batch) +
// GRN + LN + softmax + dense MFMA. grid 256 (batch), block 512.
// ---------------------------------------------------------------------------
__global__ __launch_bounds__(512) void k_tail(const unsigned* __restrict__ partial_p,
                                              const unsigned short* __restrict__ xbf,
                                              const unsigned short* __restrict__ WdTg,
                                              const float* __restrict__ b2,
                                              const float* __restrict__ W1,
                                              const float* __restrict__ b1,
                                              const float* __restrict__ Wg,
                                              const float* __restrict__ bg,
                                              const float* __restrict__ Wv,
                                              const float* __restrict__ bv,
                                              const float* __restrict__ bs,
                                              const float* __restrict__ gamma,
                                              const float* __restrict__ beta,
                                              const float* __restrict__ bd,
                                              float* __restrict__ out) {
    __shared__ float hs[128], ss[128], h2s[128];
    __shared__ float red4[4][128], rtmp[2][256];
    __shared__ float ys[128], es[128], wts[128];

    int b = blockIdx.x, tid = threadIdx.x;
    int lane = tid & 63;
    int l15 = lane & 15, lg = lane >> 4;

    {   // split-K reduce over 32 chunks (contiguous [ch][col] span), unpack
        int c = tid & 255, h = tid >> 8;
        float s = 0.f;
        const unsigned* Pp = partial_p + (size_t)(b >> 1) * RPSTRIDE + c;
        bool hi = (b & 1) != 0;
        #pragma unroll 8
        for (int ch = h; ch < NCH; ch += 2) {
            unsigned u = Pp[ch * 256];
            unsigned hw = hi ? (u & 0xffff0000u) : (u << 16);
            s += __builtin_bit_cast(float, hw);
        }
        rtmp[h][c] = s;
    }
    __syncthreads();
    if (tid < 256) {
        float rsum = rtmp[0][tid] + rtmp[1][tid];
        if (tid < 128) {
            float hp = rsum + b2[tid];
            hs[tid] = hp > 0.f ? hp : expm1f(hp);
        } else {
            ss[tid - 128] = rsum + bs[tid - 128];
        }
    }
    __syncthreads();

    int c = tid & 127;
    {   // h2 = h1 @ W1 + b1, k split in 4 quarters
        int qt = tid >> 7;
        float s = 0.f;
        int kbq = qt * 32;
        #pragma unroll 8
        for (int k = 0; k < 32; ++k) s += hs[kbq + k] * W1[(size_t)(kbq + k) * 128 + c];
        red4[qt][c] = s;
    }
    __syncthreads();
    if (tid < 128)
        h2s[tid] = red4[0][tid] + red4[1][tid] + red4[2][tid] + red4[3][tid] + b1[tid];
    __syncthreads();
    {   // gate / value, k split in halves
        int idx = tid >> 7, sel = idx & 1, kh = idx >> 1;
        const float* Wx = sel ? Wv : Wg;
        float s = 0.f;
        int kbq = kh * 64;
        #pragma unroll 8
        for (int k = 0; k < 64; ++k) s += h2s[kbq + k] * Wx[(size_t)(kbq + k) * 128 + c];
        red4[idx][c] = s;
    }
    __syncthreads();
    if (tid < 128) {
        float g = 1.f / (1.f + expf(-(red4[0][c] + red4[2][c] + bg[c])));
        float v = red4[1][c] + red4[3][c] + bv[c];
        ys[c] = ss[c] + g * v;
    }
    __syncthreads();
    if (tid < 128) {
        float sum = 0.f, sq = 0.f;
        for (int k = 0; k < 128; ++k) { float v = ys[k]; sum += v; sq += v * v; }
        float mu = sum * (1.f / 128.f);
        float var = sq * (1.f / 128.f) - mu * mu;
        float rs = rsqrtf(var + LN_EPS);
        es[c] = (ys[c] - mu) * rs * gamma[c] + beta[c];
    }
    __syncthreads();
    if (tid < 128) {
        float m = -1e30f;
        for (int k = 0; k < 128; ++k) m = fmaxf(m, es[k]);
        ys[c] = expf(es[c] - m);
    }
    __syncthreads();
    if (tid < 128) {
        float se = 0.f;
        for (int k = 0; k < 128; ++k) se += ys[k];
        wts[c] = ys[c] / se;
    }
    __syncthreads();

    // dense: out[t][d] = (sum_k xbf[t][k] WdTg[d][k] + bd[d]) * wts[d]
    int w4 = tid >> 6;
    const unsigned short* xrow = xbf + (size_t)b * 8192;
    f32x4 dacc[4];
    #pragma unroll
    for (int fm = 0; fm < 4; ++fm) dacc[fm] = (f32x4){0.f, 0.f, 0.f, 0.f};
    #pragma unroll
    for (int ks = 0; ks < 4; ++ks) {
        bf16x8 av[4], bv2;
        #pragma unroll
        for (int fm = 0; fm < 4; ++fm)
            av[fm] = *(const bf16x8*)(xrow + (size_t)(fm * 16 + l15) * 128 + ks * 32 + lg * 8);
        bv2 = *(const bf16x8*)(WdTg + (size_t)(w4 * 16 + l15) * 128 + ks * 32 + lg * 8);
        #pragma unroll
        for (int fm = 0; fm < 4; ++fm)
            dacc[fm] = __builtin_amdgcn_mfma_f32_16x16x32_bf16(av[fm], bv2, dacc[fm], 0, 0, 0);
    }
    int dcol = w4 * 16 + l15;
    float bdv = bd[dcol], wtv = wts[dcol];
    #pragma unroll
    for (int fm = 0; fm < 4; ++fm)
        #pragma unroll
        for (int rr = 0; rr < 4; ++rr) {
            int t = fm * 16 + lg * 4 + rr;
            out[(size_t)b * 8192 + (size_t)t * 128 + dcol] = (dacc[fm][rr] + bdv) * wtv;
        }
}

// ---------------------------------------------------------------------------
extern "C" void kernel_launch(void* const* d_in, const int* in_sizes, int n_in,
                              void* d_out, int out_size, void* d_ws, size_t ws_size,
                              hipStream_t stream) {
    const float* inputs = (const float*)d_in[0];
    const float* tk     = (const float*)d_in[1];
    const float* Wd     = (const float*)d_in[2];
    const float* bd     = (const float*)d_in[3];
    const float* W2     = (const float*)d_in[4];
    const float* b2     = (const float*)d_in[5];
    const float* W1     = (const float*)d_in[6];
    const float* b1     = (const float*)d_in[7];
    const float* Wg     = (const float*)d_in[8];
    const float* bg     = (const float*)d_in[9];
    const float* Wv     = (const float*)d_in[10];
    const float* bv     = (const float*)d_in[11];
    const float* Wsk    = (const float*)d_in[12];
    const float* bs     = (const float*)d_in[13];
    const float* gamma  = (const float*)d_in[14];
    const float* beta   = (const float*)d_in[15];
    float* out = (float*)d_out;

    char* ws = (char*)d_ws;
    unsigned short* sig  = (unsigned short*)ws;                 //  8,454,144 B
    unsigned* partial_p  = (unsigned*)(ws + 8454144);           //  4,194,304 B
    unsigned short* xbf  = (unsigned short*)(ws + 12648448);    //  4,194,304 B
    unsigned short* WdTg = (unsigned short*)(ws + 16842752);    //     32,768 B

    k_sig <<<257, 512, 0, stream>>>(inputs, tk, Wd, sig, xbf, WdTg);
    k_gemm<<<512, 512, 0, stream>>>(sig, W2, Wsk, partial_p);
    k_tail<<<256, 512, 0, stream>>>(partial_p, xbf, WdTg, b2, W1, b1, Wg, bg, Wv, bv,
                                    bs, gamma, beta, bd, out);
}